// Round 2
// baseline (192.645 us; speedup 1.0000x reference)
//
#include <hip/hip_runtime.h>

#define BATCH 2
#define SEQ 2048
#define DMODEL 1024
#define NH 16
#define HD 64
#define M_TOT (BATCH*SEQ)   // 4096
#define N_TOT (3*DMODEL)    // 3072
#define K_TOT (DMODEL)      // 1024
#define NQK   (2*DMODEL)    // 2048  (Q|K buffer width)
// 1/sqrt(64) * log2(e), folded into Q at the GEMM epilogue -> softmax is bare exp2
#define QSCALE 0.18033688011112042f

typedef __attribute__((ext_vector_type(8)))  _Float16 f16x8;
typedef __attribute__((ext_vector_type(4)))  float    f32x4;
typedef __attribute__((ext_vector_type(16))) float    f32x16;

static __device__ __forceinline__ unsigned short f2h(float f) {
  _Float16 h = (_Float16)f;        // v_cvt_f16_f32, RTNE
  return __builtin_bit_cast(unsigned short, h);
}

static __device__ __forceinline__ unsigned pk2h(float a, float b) {
  return (unsigned)f2h(a) | ((unsigned)f2h(b) << 16);
}

static __device__ __forceinline__ f32x16 zero16() {
  f32x16 z;
  #pragma unroll
  for (int i = 0; i < 16; ++i) z[i] = 0.f;
  return z;
}

// async 16B global->LDS (wave-uniform LDS base + lane*16 layout required;
// the GLOBAL source is per-lane -> swizzled LDS layouts via pre-swizzled src)
static __device__ __forceinline__ void async16(const unsigned short* g, unsigned short* l) {
  __builtin_amdgcn_global_load_lds(
      (const __attribute__((address_space(1))) unsigned*)g,
      (__attribute__((address_space(3))) unsigned*)l, 16, 0, 0);
}

// ---------------------------------------------------------------------------
// Kernel 0: fp32 -> fp16 cast, 8 elems/thread
// ---------------------------------------------------------------------------
__global__ __launch_bounds__(256) void cast_f16(
    const float* __restrict__ src, unsigned short* __restrict__ dst, int n8)
{
  int i = blockIdx.x * 256 + threadIdx.x;
  if (i >= n8) return;
  float4 v0 = ((const float4*)src)[2*i];
  float4 v1 = ((const float4*)src)[2*i + 1];
  uint4 pk;
  pk.x = (unsigned)f2h(v0.x) | ((unsigned)f2h(v0.y) << 16);
  pk.y = (unsigned)f2h(v0.z) | ((unsigned)f2h(v0.w) << 16);
  pk.z = (unsigned)f2h(v1.x) | ((unsigned)f2h(v1.y) << 16);
  pk.w = (unsigned)f2h(v1.z) | ((unsigned)f2h(v1.w) << 16);
  ((uint4*)dst)[i] = pk;
}

// ---------------------------------------------------------------------------
// Kernel 1: merged QKV GEMM, 128x128 tile, BK=32, DOUBLE-BUFFERED LDS with
// counted vmcnt + raw s_barrier (prefetch for step t+1 stays in flight across
// the barrier; no vmcnt(0) drain in the main loop).
//   bx <  16: QK[m][n] = x·W^T + b   (Q columns pre-scaled by QSCALE)
//   bx >= 16: V blocks with OPERANDS SWAPPED (A = W_v rows, B = x rows) so
//             D = W_v·x^T = V^T, written straight into VT[(b*16+h)*64+d][s].
// LDS [128][32] layout: b128 fragment reads are inherently conflict-free
// (8 lane-groups x 4-bank sets, 8 phases = wave64-b128 minimum) -> no swizzle.
// ---------------------------------------------------------------------------
__global__ __launch_bounds__(256) void qkv_gemm_mfma(
    const unsigned short* __restrict__ Xh,
    const unsigned short* __restrict__ Wh,
    const float* __restrict__ bias,
    unsigned short* __restrict__ QK,
    unsigned short* __restrict__ VT)
{
  __shared__ unsigned short As[2][128][32];   // 16 KB
  __shared__ unsigned short Bs[2][128][32];   // 16 KB

  const int tid  = threadIdx.x;
  const int wave = tid >> 6;
  const int lane = tid & 63;
  const int l15  = lane & 15;
  const int quad = lane >> 4;

  const bool isV = (blockIdx.x >= (NQK/128));
  const int n0 = (isV ? (blockIdx.x - NQK/128) : blockIdx.x) * 128;
  const int m0 = blockIdx.y * 128;

  // A rows = MFMA m-side, B rows = MFMA n-side
  const unsigned short* Arows = isV ? (Wh + (size_t)(NQK + n0) * K_TOT)
                                    : (Xh + (size_t)m0 * K_TOT);
  const unsigned short* Brows = isV ? (Xh + (size_t)m0 * K_TOT)
                                    : (Wh + (size_t)n0 * K_TOT);

  const int srow = tid >> 2;            // 0..63
  const int skc  = (tid & 3) * 8;       // 0,8,16,24
  const unsigned short* Ag0 = Arows + (size_t)srow * K_TOT + skc;
  const unsigned short* Ag1 = Arows + (size_t)(64 + srow) * K_TOT + skc;
  const unsigned short* Bg0 = Brows + (size_t)srow * K_TOT + skc;
  const unsigned short* Bg1 = Brows + (size_t)(64 + srow) * K_TOT + skc;
  unsigned short* Al = &As[0][0][0] + tid * 8;   // buffer stride 4096 shorts
  unsigned short* Bl = &Bs[0][0][0] + tid * 8;

  const int wm = (wave & 1) * 64;
  const int wn = (wave >> 1) * 64;

  f32x4 acc[4][4];
  #pragma unroll
  for (int i = 0; i < 4; ++i)
    #pragma unroll
    for (int j = 0; j < 4; ++j) acc[i][j] = (f32x4){0.f,0.f,0.f,0.f};

  auto STAGE = [&](int k0, int bb) {
    async16(Ag0 + k0, Al + bb*4096);
    async16(Ag1 + k0, Al + bb*4096 + 2048);
    async16(Bg0 + k0, Bl + bb*4096);
    async16(Bg1 + k0, Bl + bb*4096 + 2048);
  };

  auto COMPUTE = [&](int bb) {
    f16x8 af[4], bf[4];
    #pragma unroll
    for (int i = 0; i < 4; ++i)
      af[i] = *(const f16x8*)&As[bb][wm + i*16 + l15][quad*8];
    #pragma unroll
    for (int j = 0; j < 4; ++j)
      bf[j] = *(const f16x8*)&Bs[bb][wn + j*16 + l15][quad*8];
    __builtin_amdgcn_s_setprio(1);
    #pragma unroll
    for (int i = 0; i < 4; ++i)
      #pragma unroll
      for (int j = 0; j < 4; ++j)
        acc[i][j] = __builtin_amdgcn_mfma_f32_16x16x32_f16(af[i], bf[j], acc[i][j], 0, 0, 0);
    __builtin_amdgcn_s_setprio(0);
  };

  STAGE(0, 0);
  for (int t = 0; t < K_TOT/32 - 1; ++t) {
    STAGE((t+1)*32, (t+1) & 1);                      // prefetch next K-step
    asm volatile("s_waitcnt vmcnt(4)" ::: "memory"); // own step-t loads done
    __builtin_amdgcn_s_barrier();                    // all waves' step-t done
    COMPUTE(t & 1);
    __builtin_amdgcn_s_barrier();                    // reads done before reuse
  }
  asm volatile("s_waitcnt vmcnt(0)" ::: "memory");
  __builtin_amdgcn_s_barrier();
  COMPUTE((K_TOT/32 - 1) & 1);

  if (!isV) {
    // D: col(l15) = n (weight), row(quad*4+r) = m (x row)
    const float sc = (n0 < DMODEL) ? QSCALE : 1.0f;
    float bv[4];
    #pragma unroll
    for (int j = 0; j < 4; ++j) bv[j] = bias[n0 + wn + j*16 + l15];
    #pragma unroll
    for (int i = 0; i < 4; ++i)
      #pragma unroll
      for (int j = 0; j < 4; ++j)
        #pragma unroll
        for (int r = 0; r < 4; ++r) {
          const size_t row = (size_t)(m0 + wm + i*16 + quad*4 + r);
          QK[row * NQK + n0 + wn + j*16 + l15] = f2h((acc[i][j][r] + bv[j]) * sc);
        }
  } else {
    // swapped: D col(l15) = x row (seq), D row(quad*4+r) = weight row (V col)
    const int bidx  = m0 >> 11;              // batch (m tiles don't straddle 2048)
    const int sbase = (m0 & 2047) + wn;
    #pragma unroll
    for (int i = 0; i < 4; ++i)
      #pragma unroll
      for (int r = 0; r < 4; ++r) {
        const int nn = n0 + wm + i*16 + quad*4 + r;         // V col 0..1023
        const float bb = bias[NQK + nn];
        unsigned short* drow =
            VT + ((size_t)(bidx*NH + (nn >> 6)) * HD + (nn & 63)) * SEQ + sbase;
        #pragma unroll
        for (int j = 0; j < 4; ++j)
          drow[j*16 + l15] = f2h(acc[i][j][r] + bb);        // 16 consecutive s
      }
  }
}

// ---------------------------------------------------------------------------
// Kernel 2: flash attention, 32x32x16 MFMA.
// Staging = pre-swizzled global_load_lds (K from QK buf, V^T from VT buf),
// double-buffered with counted vmcnt(4) + raw s_barrier.
// P never touches LDS: after swapped QK^T, lane L holds P[q=L&31] for keys
// r+8s+4*h32; the PV A-frag (keys 16f+8*h32+{0..7}) is assembled in-register
// from the lane's own half-runs plus the partner lane's (L^32, same q) via
// 2x __shfl_xor(32) + cndmask per MFMA  (T12 mechanism, shfl primitive).
// Q pre-scaled by QSCALE in the GEMM -> softmax is bare exp2f.
// K/V LDS layouts linear [64][64]; logical col-group g lives at phys (g+row)&7.
// ---------------------------------------------------------------------------
__global__ __launch_bounds__(256) void attn_mfma3(
    const unsigned short* __restrict__ QK,
    const unsigned short* __restrict__ VT,
    float* __restrict__ out)
{
  __shared__ unsigned short Ks[2][64][64];   // 16 KB  [buf][key][d swz]
  __shared__ unsigned short Vs[2][64][64];   // 16 KB  [buf][d][key swz]
  __shared__ float Dn[4][32];

  const int tid  = threadIdx.x;
  const int wv   = tid >> 6;
  const int lane = tid & 63;
  const int l31  = lane & 31;
  const int h32  = lane >> 5;

  const int qt = blockIdx.x;                 // 0..15
  const int hh = blockIdx.y;                 // 0..15
  const int b  = blockIdx.z;                 // 0..1
  const int q0 = qt*128 + wv*32;

  // Q B-frags straight from global (pre-scaled)
  f16x8 qf[4];
  {
    const unsigned short* qrow = QK + (size_t)(b*SEQ + q0 + l31) * NQK + hh*HD;
    #pragma unroll
    for (int f = 0; f < 4; ++f)
      qf[f] = *(const f16x8*)(qrow + f*16 + h32*8);
  }

  const unsigned short* Kg = QK + (size_t)b*SEQ*NQK + DMODEL + hh*HD;
  const unsigned short* Vg = VT + (size_t)(b*NH + hh) * HD * SEQ;

  const int sr = tid >> 3;
  const int sp = tid & 7;
  const int sg = ((sp - sr) & 7) * 8;

  const unsigned short* kg0 = Kg + (size_t)sr      * NQK + sg;
  const unsigned short* kg1 = Kg + (size_t)(sr+32) * NQK + sg;
  const unsigned short* vg0 = Vg + (size_t)sr      * SEQ + sg;
  const unsigned short* vg1 = Vg + (size_t)(sr+32) * SEQ + sg;
  unsigned short* kl = &Ks[0][0][0] + tid*8;
  unsigned short* vl = &Vs[0][0][0] + tid*8;

  f32x16 oacc[2];
  oacc[0] = zero16();
  oacc[1] = zero16();
  float dsum = 0.f;

  auto STAGE = [&](int kt, int bb) {
    const size_t krow = (size_t)kt * 64 * NQK;   // K: advance rows (keys)
    const int    kcol = kt * 64;                 // V^T: advance cols (keys)
    async16(kg0 + krow, kl + bb*4096);
    async16(kg1 + krow, kl + bb*4096 + 2048);
    async16(vg0 + kcol, vl + bb*4096);
    async16(vg1 + kcol, vl + bb*4096 + 2048);
  };

  auto COMPUTE = [&](int bb) {
    const unsigned short* ks = &Ks[bb][0][0];
    const unsigned short* vs = &Vs[bb][0][0];

    // ---- S^T = K.Q^T : rows=key, cols=q ----
    f32x16 sa[2];
    sa[0] = zero16();
    sa[1] = zero16();
    __builtin_amdgcn_s_setprio(1);
    #pragma unroll
    for (int f = 0; f < 4; ++f) {
      const int g = f*2 + h32;
      #pragma unroll
      for (int kb = 0; kb < 2; ++kb) {
        const int row = kb*32 + l31;
        f16x8 kf = *(const f16x8*)(ks + row*64 + ((g + row) & 7) * 8);
        sa[kb] = __builtin_amdgcn_mfma_f32_32x32x16_f16(kf, qf[f], sa[kb], 0, 0, 0);
      }
    }
    __builtin_amdgcn_s_setprio(0);

    // ---- exp2 (scale pre-folded) in place + denom accum ----
    #pragma unroll
    for (int kb = 0; kb < 2; ++kb)
      #pragma unroll
      for (int i = 0; i < 16; ++i) {
        float p = exp2f(sa[kb][i]);
        dsum += p;
        sa[kb][i] = p;
      }

    // ---- O += P.V : P A-frags assembled in-register (no LDS) ----
    // Lane (q,h) owns keys 8g+4h+{0..3} of group g (reg s=g&3, r=0..3).
    // MFMA f needs lane-half h to supply keys 16f+8h+{0..7} = group 2f+h.
    __builtin_amdgcn_s_setprio(1);
    #pragma unroll
    for (int f = 0; f < 4; ++f) {
      const int kb = f >> 1;
      const int ge = (f & 1) * 2;                    // even group slot (s)
      unsigned A = pk2h(sa[kb][ge*4+0], sa[kb][ge*4+1]);  // g=2f, own half {0,1}
      unsigned B = pk2h(sa[kb][ge*4+2], sa[kb][ge*4+3]);  // g=2f, own half {2,3}
      unsigned C = pk2h(sa[kb][ge*4+4], sa[kb][ge*4+5]);  // g=2f+1, own {0,1}
      unsigned D = pk2h(sa[kb][ge*4+6], sa[kb][ge*4+7]);  // g=2f+1, own {2,3}
      // h=1 sends A (keys 16f+4..5) to h=0; h=0 sends C (16f+8..9) to h=1
      unsigned t0 = (unsigned)__shfl_xor((int)(h32 ? A : C), 32, 64);
      // h=1 sends B (keys 16f+6..7); h=0 sends D (16f+10..11)
      unsigned t1 = (unsigned)__shfl_xor((int)(h32 ? B : D), 32, 64);
      uint4 pw;
      pw.x = h32 ? t0 : A;    // keys 16f+8h+{0,1}
      pw.y = h32 ? t1 : B;    // keys 16f+8h+{2,3}
      pw.z = h32 ? C : t0;    // keys 16f+8h+{4,5}
      pw.w = h32 ? D : t1;    // keys 16f+8h+{6,7}
      f16x8 pf = __builtin_bit_cast(f16x8, pw);
      const int g = f*2 + h32;
      #pragma unroll
      for (int jd = 0; jd < 2; ++jd) {
        const int row = jd*32 + l31;
        f16x8 vf = *(const f16x8*)(vs + row*64 + ((g + row) & 7) * 8);
        oacc[jd] = __builtin_amdgcn_mfma_f32_32x32x16_f16(pf, vf, oacc[jd], 0, 0, 0);
      }
    }
    __builtin_amdgcn_s_setprio(0);
  };

  // ---- double-buffered main loop: counted vmcnt, raw barriers ----
  STAGE(0, 0);
  for (int kt = 0; kt < SEQ/64 - 1; ++kt) {
    STAGE(kt + 1, (kt + 1) & 1);                    // prefetch next tile
    asm volatile("s_waitcnt vmcnt(4)" ::: "memory"); // own tile-kt loads done
    __builtin_amdgcn_s_barrier();                    // all waves' kt loads done
    COMPUTE(kt & 1);
    __builtin_amdgcn_s_barrier();                    // reads done before reuse
  }
  asm volatile("s_waitcnt vmcnt(0)" ::: "memory");
  __builtin_amdgcn_s_barrier();
  COMPUTE((SEQ/64 - 1) & 1);

  // ---- denom: combine the two half-wave partial sums (same q) ----
  dsum += __shfl_xor(dsum, 32, 64);
  Dn[wv][l31] = 1.f / dsum;

  // ---- write O: row q = g4*8 + h32*4 + r, col d = jd*32 + l31 ----
  #pragma unroll
  for (int jd = 0; jd < 2; ++jd) {
    #pragma unroll
    for (int g4 = 0; g4 < 4; ++g4) {
      #pragma unroll
      for (int r = 0; r < 4; ++r) {
        const int qrow = g4*8 + h32*4 + r;
        const float oval = oacc[jd][g4*4 + r] * Dn[wv][qrow];
        out[(size_t)(b*SEQ + q0 + qrow) * DMODEL + hh*HD + jd*32 + l31] = oval;
      }
    }
  }
}

extern "C" void kernel_launch(void* const* d_in, const int* in_sizes, int n_in,
                              void* d_out, int out_size, void* d_ws, size_t ws_size,
                              hipStream_t stream) {
  const float* x    = (const float*)d_in[0];   // [2,2048,1024] fp32
  const float* W    = (const float*)d_in[1];   // [3072,1024]   fp32
  const float* bias = (const float*)d_in[2];   // [3072]        fp32
  float* out = (float*)d_out;                  // [2,2048,1024] fp32

  unsigned short* qk = (unsigned short*)d_ws;                   // 4096*2048 f16 (Q scaled | K)
  unsigned short* vt = qk + (size_t)M_TOT * NQK;                // [2*16][64][2048] f16 = V^T
  unsigned short* xh = vt + (size_t)BATCH * NH * HD * SEQ;      // 4096*1024 f16
  unsigned short* wh = xh + (size_t)M_TOT * K_TOT;              // 3072*1024 f16

  cast_f16<<<(M_TOT*K_TOT/8 + 255)/256, 256, 0, stream>>>(x, xh, M_TOT*K_TOT/8);
  cast_f16<<<(N_TOT*K_TOT/8 + 255)/256, 256, 0, stream>>>(W, wh, N_TOT*K_TOT/8);

  dim3 g1(N_TOT/128, M_TOT/128);               // 24 x 32 = 768 blocks (16 QK + 8 V)
  qkv_gemm_mfma<<<g1, 256, 0, stream>>>(xh, wh, bias, qk, vt);

  dim3 g2(SEQ/128, NH, BATCH);                 // 16 x 16 x 2 = 512 blocks
  attn_mfma3<<<g2, 256, 0, stream>>>(qk, vt, out);
}

// Round 4
// 187.625 us; speedup vs baseline: 1.0268x; 1.0268x over previous
//
#include <hip/hip_runtime.h>

#define BATCH 2
#define SEQ 2048
#define DMODEL 1024
#define NH 16
#define HD 64
#define M_TOT (BATCH*SEQ)   // 4096
#define N_TOT (3*DMODEL)    // 3072
#define K_TOT (DMODEL)      // 1024
#define NQK   (2*DMODEL)    // 2048  (Q|K buffer width)
// 1/sqrt(64) * log2(e), folded into Q at the GEMM epilogue -> softmax is bare exp2
#define QSCALE 0.18033688011112042f

typedef __attribute__((ext_vector_type(8)))  _Float16 f16x8;
typedef __attribute__((ext_vector_type(4)))  float    f32x4;
typedef __attribute__((ext_vector_type(16))) float    f32x16;

static __device__ __forceinline__ unsigned short f2h(float f) {
  _Float16 h = (_Float16)f;        // v_cvt_f16_f32, RTNE
  return __builtin_bit_cast(unsigned short, h);
}

static __device__ __forceinline__ f32x16 zero16() {
  f32x16 z;
  #pragma unroll
  for (int i = 0; i < 16; ++i) z[i] = 0.f;
  return z;
}

// async 16B global->LDS (wave-uniform LDS base + lane*16 layout required;
// the GLOBAL source is per-lane -> swizzled LDS layouts via pre-swizzled src)
static __device__ __forceinline__ void async16(const unsigned short* g, unsigned short* l) {
  __builtin_amdgcn_global_load_lds(
      (const __attribute__((address_space(1))) unsigned*)g,
      (__attribute__((address_space(3))) unsigned*)l, 16, 0, 0);
}

// Raw s_barrier is IntrNoMem in LLVM: loads/LDS-writes legally move across it.
// (Round-3 race root cause.) Fence it on BOTH sides at IR level (asm memory
// clobber) and MIR level (sched_barrier(0)). Emits only the s_barrier.
static __device__ __forceinline__ void barrier_fenced() {
  asm volatile("" ::: "memory");
  __builtin_amdgcn_sched_barrier(0);
  __builtin_amdgcn_s_barrier();
  __builtin_amdgcn_sched_barrier(0);
  asm volatile("" ::: "memory");
}

// ---------------------------------------------------------------------------
// Kernel 0: fp32 -> fp16 cast for BOTH x and W in one launch (8 elems/thread)
// ---------------------------------------------------------------------------
__global__ __launch_bounds__(256) void cast_f16_2(
    const float* __restrict__ xsrc, const float* __restrict__ wsrc,
    unsigned short* __restrict__ xdst, unsigned short* __restrict__ wdst,
    int n8x, int n8tot)
{
  int i = blockIdx.x * 256 + threadIdx.x;
  if (i >= n8tot) return;
  const float* src;
  unsigned short* dst;
  int idx;
  if (i < n8x) { src = xsrc; dst = xdst; idx = i; }
  else         { src = wsrc; dst = wdst; idx = i - n8x; }
  float4 v0 = ((const float4*)src)[2*idx];
  float4 v1 = ((const float4*)src)[2*idx + 1];
  uint4 pk;
  pk.x = (unsigned)f2h(v0.x) | ((unsigned)f2h(v0.y) << 16);
  pk.y = (unsigned)f2h(v0.z) | ((unsigned)f2h(v0.w) << 16);
  pk.z = (unsigned)f2h(v1.x) | ((unsigned)f2h(v1.y) << 16);
  pk.w = (unsigned)f2h(v1.z) | ((unsigned)f2h(v1.w) << 16);
  ((uint4*)dst)[idx] = pk;
}

// ---------------------------------------------------------------------------
// Kernel 1: merged QKV GEMM, 128x128 tile, BK=32, TRIPLE-buffered LDS with
// ONE fenced barrier per K-step: STAGE(t+2) is issued after the barrier, so
// it cannot collide with COMPUTE(t-1) reads (those retired before the
// barrier; the post-barrier fence pins STAGE below it). vmcnt(4) before the
// barrier proves the wave's own tile-t loads landed (in-order retire, m135).
//   bx <  16: QK[m][n] = x·W^T + b   (Q columns pre-scaled by QSCALE)
//   bx >= 16: V blocks with OPERANDS SWAPPED (A = W_v rows, B = x rows) so
//             D = W_v·x^T = V^T, written straight into VT[(b*16+h)*64+d][s].
// LDS [128][32]: b128 fragment reads conflict-pattern identical to m97's.
// No setprio here (m190: hurts lockstep GEMM).
// ---------------------------------------------------------------------------
__global__ __launch_bounds__(256) void qkv_gemm_mfma(
    const unsigned short* __restrict__ Xh,
    const unsigned short* __restrict__ Wh,
    const float* __restrict__ bias,
    unsigned short* __restrict__ QK,
    unsigned short* __restrict__ VT)
{
  __shared__ unsigned short As[3][128][32];   // 24 KB
  __shared__ unsigned short Bs[3][128][32];   // 24 KB

  const int tid  = threadIdx.x;
  const int wave = tid >> 6;
  const int lane = tid & 63;
  const int l15  = lane & 15;
  const int quad = lane >> 4;

  const bool isV = (blockIdx.x >= (NQK/128));
  const int n0 = (isV ? (blockIdx.x - NQK/128) : blockIdx.x) * 128;
  const int m0 = blockIdx.y * 128;

  const unsigned short* Arows = isV ? (Wh + (size_t)(NQK + n0) * K_TOT)
                                    : (Xh + (size_t)m0 * K_TOT);
  const unsigned short* Brows = isV ? (Xh + (size_t)m0 * K_TOT)
                                    : (Wh + (size_t)n0 * K_TOT);

  const int srow = tid >> 2;            // 0..63
  const int skc  = (tid & 3) * 8;       // 0,8,16,24
  const unsigned short* Ag0 = Arows + (size_t)srow * K_TOT + skc;
  const unsigned short* Ag1 = Arows + (size_t)(64 + srow) * K_TOT + skc;
  const unsigned short* Bg0 = Brows + (size_t)srow * K_TOT + skc;
  const unsigned short* Bg1 = Brows + (size_t)(64 + srow) * K_TOT + skc;
  unsigned short* Al = &As[0][0][0] + tid * 8;   // buffer stride 4096 shorts
  unsigned short* Bl = &Bs[0][0][0] + tid * 8;

  const int wm = (wave & 1) * 64;
  const int wn = (wave >> 1) * 64;

  f32x4 acc[4][4];
  #pragma unroll
  for (int i = 0; i < 4; ++i)
    #pragma unroll
    for (int j = 0; j < 4; ++j) acc[i][j] = (f32x4){0.f,0.f,0.f,0.f};

  auto STAGE = [&](int k0, int bb) {
    async16(Ag0 + k0, Al + bb*4096);
    async16(Ag1 + k0, Al + bb*4096 + 2048);
    async16(Bg0 + k0, Bl + bb*4096);
    async16(Bg1 + k0, Bl + bb*4096 + 2048);
  };

  auto COMPUTE = [&](int bb) {
    f16x8 af[4], bf[4];
    #pragma unroll
    for (int i = 0; i < 4; ++i)
      af[i] = *(const f16x8*)&As[bb][wm + i*16 + l15][quad*8];
    #pragma unroll
    for (int j = 0; j < 4; ++j)
      bf[j] = *(const f16x8*)&Bs[bb][wn + j*16 + l15][quad*8];
    #pragma unroll
    for (int i = 0; i < 4; ++i)
      #pragma unroll
      for (int j = 0; j < 4; ++j)
        acc[i][j] = __builtin_amdgcn_mfma_f32_16x16x32_f16(af[i], bf[j], acc[i][j], 0, 0, 0);
  };

  STAGE(0, 0);
  STAGE(32, 1);
  int bs = 2, bc = 0;                                // stage / compute buffers
  for (int t = 0; t < K_TOT/32 - 2; ++t) {
    asm volatile("s_waitcnt vmcnt(4)" ::: "memory"); // own tile-t loads landed
    barrier_fenced();                                // all waves' tile-t landed
    STAGE((t+2)*32, bs);                             // safe: t-1 reads retired
    COMPUTE(bc);
    bs = (bs == 2) ? 0 : bs + 1;
    bc = (bc == 2) ? 0 : bc + 1;
  }
  asm volatile("s_waitcnt vmcnt(4)" ::: "memory");
  barrier_fenced();
  COMPUTE(bc);
  bc = (bc == 2) ? 0 : bc + 1;
  asm volatile("s_waitcnt vmcnt(0)" ::: "memory");
  barrier_fenced();
  COMPUTE(bc);

  if (!isV) {
    // D: col(l15) = n (weight), row(quad*4+r) = m (x row)
    const float sc = (n0 < DMODEL) ? QSCALE : 1.0f;
    float bv[4];
    #pragma unroll
    for (int j = 0; j < 4; ++j) bv[j] = bias[n0 + wn + j*16 + l15];
    #pragma unroll
    for (int i = 0; i < 4; ++i)
      #pragma unroll
      for (int j = 0; j < 4; ++j)
        #pragma unroll
        for (int r = 0; r < 4; ++r) {
          const size_t row = (size_t)(m0 + wm + i*16 + quad*4 + r);
          QK[row * NQK + n0 + wn + j*16 + l15] = f2h((acc[i][j][r] + bv[j]) * sc);
        }
  } else {
    // swapped: D col(l15) = x row (seq), D row(quad*4+r) = weight row (V col)
    const int bidx  = m0 >> 11;              // batch (m tiles don't straddle 2048)
    const int sbase = (m0 & 2047) + wn;
    #pragma unroll
    for (int i = 0; i < 4; ++i)
      #pragma unroll
      for (int r = 0; r < 4; ++r) {
        const int nn = n0 + wm + i*16 + quad*4 + r;         // V col 0..1023
        const float bb = bias[NQK + nn];
        unsigned short* drow =
            VT + ((size_t)(bidx*NH + (nn >> 6)) * HD + (nn & 63)) * SEQ + sbase;
        #pragma unroll
        for (int j = 0; j < 4; ++j)
          drow[j*16 + l15] = f2h(acc[i][j][r] + bb);        // 16 consecutive s
      }
  }
}

// ---------------------------------------------------------------------------
// Kernel 2: flash attention, 32x32x16 MFMA  (round-1 P-through-LDS compute,
// proven 77.6 us). Staging = pre-swizzled global_load_lds; TRIPLE-buffered
// K/V with ONE fenced barrier per tile (same argument as the GEMM).
// Q pre-scaled by QSCALE in the GEMM -> softmax is bare exp2f.
// K/V LDS layouts linear [64][64]; logical col-group g lives at phys (g+row)&7.
// ---------------------------------------------------------------------------
__global__ __launch_bounds__(256) void attn_mfma3(
    const unsigned short* __restrict__ QK,
    const unsigned short* __restrict__ VT,
    float* __restrict__ out)
{
  __shared__ unsigned short Ks[3][64][64];   // 24 KB  [buf][key][d swz]
  __shared__ unsigned short Vs[3][64][64];   // 24 KB  [buf][d][key swz]
  __shared__ unsigned short Ps[4][32][72];   // 18 KB  [wave][q][key swz]
  __shared__ float Dn[4][32];

  const int tid  = threadIdx.x;
  const int wv   = tid >> 6;
  const int lane = tid & 63;
  const int l31  = lane & 31;
  const int h32  = lane >> 5;
  const int qsw  = l31 >> 3;

  const int qt = blockIdx.x;                 // 0..15
  const int hh = blockIdx.y;                 // 0..15
  const int b  = blockIdx.z;                 // 0..1
  const int q0 = qt*128 + wv*32;

  // Q B-frags straight from global (pre-scaled)
  f16x8 qf[4];
  {
    const unsigned short* qrow = QK + (size_t)(b*SEQ + q0 + l31) * NQK + hh*HD;
    #pragma unroll
    for (int f = 0; f < 4; ++f)
      qf[f] = *(const f16x8*)(qrow + f*16 + h32*8);
  }

  const unsigned short* Kg = QK + (size_t)b*SEQ*NQK + DMODEL + hh*HD;
  const unsigned short* Vg = VT + (size_t)(b*NH + hh) * HD * SEQ;

  const int sr = tid >> 3;
  const int sp = tid & 7;
  const int sg = ((sp - sr) & 7) * 8;

  const unsigned short* kg0 = Kg + (size_t)sr      * NQK + sg;
  const unsigned short* kg1 = Kg + (size_t)(sr+32) * NQK + sg;
  const unsigned short* vg0 = Vg + (size_t)sr      * SEQ + sg;
  const unsigned short* vg1 = Vg + (size_t)(sr+32) * SEQ + sg;
  unsigned short* kl = &Ks[0][0][0] + tid*8;
  unsigned short* vl = &Vs[0][0][0] + tid*8;

  f32x16 oacc[2];
  oacc[0] = zero16();
  oacc[1] = zero16();
  float dsum = 0.f;

  auto STAGE = [&](int kt, int bb) {
    const size_t krow = (size_t)kt * 64 * NQK;   // K: advance rows (keys)
    const int    kcol = kt * 64;                 // V^T: advance cols (keys)
    async16(kg0 + krow, kl + bb*4096);
    async16(kg1 + krow, kl + bb*4096 + 2048);
    async16(vg0 + kcol, vl + bb*4096);
    async16(vg1 + kcol, vl + bb*4096 + 2048);
  };

  auto COMPUTE = [&](int bb) {
    const unsigned short* ks = &Ks[bb][0][0];
    const unsigned short* vs = &Vs[bb][0][0];

    // ---- S^T = K.Q^T : rows=key (2 blocks of 32), cols=q ----
    f32x16 sa[2];
    sa[0] = zero16();
    sa[1] = zero16();
    __builtin_amdgcn_s_setprio(1);
    #pragma unroll
    for (int f = 0; f < 4; ++f) {
      const int g = f*2 + h32;
      #pragma unroll
      for (int kb = 0; kb < 2; ++kb) {
        const int row = kb*32 + l31;
        f16x8 kf = *(const f16x8*)(ks + row*64 + ((g + row) & 7) * 8);
        sa[kb] = __builtin_amdgcn_mfma_f32_32x32x16_f16(kf, qf[f], sa[kb], 0, 0, 0);
      }
    }
    __builtin_amdgcn_s_setprio(0);

    // ---- exp2 (scale pre-folded), denom accum, P -> LDS [q][key swz] ----
    #pragma unroll
    for (int kb = 0; kb < 2; ++kb) {
      #pragma unroll
      for (int g4 = 0; g4 < 4; ++g4) {
        unsigned short hsv[4];
        #pragma unroll
        for (int r = 0; r < 4; ++r) {
          float p = exp2f(sa[kb][g4*4 + r]);
          dsum += p;
          hsv[r] = f2h(p);
        }
        unsigned short* dst =
            &Ps[wv][l31][(((kb*4 + g4) ^ qsw) & 7) * 8 + h32*4];
        uint2 pk;
        pk.x = (unsigned)hsv[0] | ((unsigned)hsv[1] << 16);
        pk.y = (unsigned)hsv[2] | ((unsigned)hsv[3] << 16);
        *(uint2*)dst = pk;   // same-wave write->read: lgkmcnt ordering suffices
      }
    }

    // ---- O += P.V : A = P[q][key], B = Vs[d][key] ----
    __builtin_amdgcn_s_setprio(1);
    #pragma unroll
    for (int f = 0; f < 4; ++f) {
      const int g = f*2 + h32;
      f16x8 pf = *(const f16x8*)&Ps[wv][l31][((g ^ qsw) & 7) * 8];
      #pragma unroll
      for (int jd = 0; jd < 2; ++jd) {
        const int row = jd*32 + l31;
        f16x8 vf = *(const f16x8*)(vs + row*64 + ((g + row) & 7) * 8);
        oacc[jd] = __builtin_amdgcn_mfma_f32_32x32x16_f16(pf, vf, oacc[jd], 0, 0, 0);
      }
    }
    __builtin_amdgcn_s_setprio(0);
  };

  // ---- triple-buffered main loop: one fenced barrier per tile ----
  STAGE(0, 0);
  STAGE(1, 1);
  int bs = 2, bc = 0;
  for (int kt = 0; kt < SEQ/64 - 2; ++kt) {
    asm volatile("s_waitcnt vmcnt(4)" ::: "memory"); // own tile-kt loads landed
    barrier_fenced();                                // all waves' tile-kt landed
    STAGE(kt + 2, bs);                               // safe: kt-1 reads retired
    COMPUTE(bc);
    bs = (bs == 2) ? 0 : bs + 1;
    bc = (bc == 2) ? 0 : bc + 1;
  }
  asm volatile("s_waitcnt vmcnt(4)" ::: "memory");
  barrier_fenced();
  COMPUTE(bc);
  bc = (bc == 2) ? 0 : bc + 1;
  asm volatile("s_waitcnt vmcnt(0)" ::: "memory");
  barrier_fenced();
  COMPUTE(bc);

  // ---- denom: combine the two half-wave partial sums (same q) ----
  dsum += __shfl_xor(dsum, 32, 64);
  Dn[wv][l31] = 1.f / dsum;          // wave-local; lgkmcnt ordering suffices

  // ---- write O: row q = g4*8 + h32*4 + r, col d = jd*32 + l31 ----
  #pragma unroll
  for (int jd = 0; jd < 2; ++jd) {
    #pragma unroll
    for (int g4 = 0; g4 < 4; ++g4) {
      #pragma unroll
      for (int r = 0; r < 4; ++r) {
        const int qrow = g4*8 + h32*4 + r;
        const float oval = oacc[jd][g4*4 + r] * Dn[wv][qrow];
        out[(size_t)(b*SEQ + q0 + qrow) * DMODEL + hh*HD + jd*32 + l31] = oval;
      }
    }
  }
}

extern "C" void kernel_launch(void* const* d_in, const int* in_sizes, int n_in,
                              void* d_out, int out_size, void* d_ws, size_t ws_size,
                              hipStream_t stream) {
  const float* x    = (const float*)d_in[0];   // [2,2048,1024] fp32
  const float* W    = (const float*)d_in[1];   // [3072,1024]   fp32
  const float* bias = (const float*)d_in[2];   // [3072]        fp32
  float* out = (float*)d_out;                  // [2,2048,1024] fp32

  unsigned short* qk = (unsigned short*)d_ws;                   // 4096*2048 f16 (Q scaled | K)
  unsigned short* vt = qk + (size_t)M_TOT * NQK;                // [2*16][64][2048] f16 = V^T
  unsigned short* xh = vt + (size_t)BATCH * NH * HD * SEQ;      // 4096*1024 f16
  unsigned short* wh = xh + (size_t)M_TOT * K_TOT;              // 3072*1024 f16

  const int n8x = M_TOT*K_TOT/8;               // 524288
  const int n8w = N_TOT*K_TOT/8;               // 393216
  cast_f16_2<<<(n8x + n8w + 255)/256, 256, 0, stream>>>(x, W, xh, wh, n8x, n8x + n8w);

  dim3 g1(N_TOT/128, M_TOT/128);               // 24 x 32 = 768 blocks (16 QK + 8 V)
  qkv_gemm_mfma<<<g1, 256, 0, stream>>>(xh, wh, bias, qk, vt);

  dim3 g2(SEQ/128, NH, BATCH);                 // 16 x 16 x 2 = 512 blocks
  attn_mfma3<<<g2, 256, 0, stream>>>(qk, vt, out);
}

// Round 5
// 183.178 us; speedup vs baseline: 1.0517x; 1.0243x over previous
//
#include <hip/hip_runtime.h>

#define BATCH 2
#define SEQ 2048
#define DMODEL 1024
#define NH 16
#define HD 64
#define M_TOT (BATCH*SEQ)   // 4096
#define N_TOT (3*DMODEL)    // 3072
#define K_TOT (DMODEL)      // 1024
#define NQK   (2*DMODEL)    // 2048  (Q|K buffer width)
// 1/sqrt(64) * log2(e), folded into Q at the GEMM epilogue -> softmax is bare exp2
#define QSCALE 0.18033688011112042f

typedef __attribute__((ext_vector_type(8)))  _Float16 f16x8;
typedef __attribute__((ext_vector_type(4)))  float    f32x4;
typedef __attribute__((ext_vector_type(16))) float    f32x16;

static __device__ __forceinline__ unsigned short f2h(float f) {
  _Float16 h = (_Float16)f;        // v_cvt_f16_f32, RTNE
  return __builtin_bit_cast(unsigned short, h);
}

static __device__ __forceinline__ f32x16 zero16() {
  f32x16 z;
  #pragma unroll
  for (int i = 0; i < 16; ++i) z[i] = 0.f;
  return z;
}

// async 16B global->LDS (wave-uniform LDS base + lane*16 layout required;
// the GLOBAL source is per-lane -> swizzled LDS layouts via pre-swizzled src)
static __device__ __forceinline__ void async16(const unsigned short* g, unsigned short* l) {
  __builtin_amdgcn_global_load_lds(
      (const __attribute__((address_space(1))) unsigned*)g,
      (__attribute__((address_space(3))) unsigned*)l, 16, 0, 0);
}

// Raw s_barrier is IntrNoMem: memory ops can legally move across it (round-3
// race). IR-level memory-clobber fences pin all memory ops (incl. the
// global_load_lds intrinsic and ds accesses) to their side of the barrier.
// NO sched_barrier(0): that pinned the whole scheduler and regressed round 4
// (m141 failure mode).
static __device__ __forceinline__ void barrier_f() {
  asm volatile("" ::: "memory");
  __builtin_amdgcn_s_barrier();
  asm volatile("" ::: "memory");
}

// ---------------------------------------------------------------------------
// Kernel 0: fp32 -> fp16 cast for BOTH x and W in one launch (8 elems/thread)
// ---------------------------------------------------------------------------
__global__ __launch_bounds__(256) void cast_f16_2(
    const float* __restrict__ xsrc, const float* __restrict__ wsrc,
    unsigned short* __restrict__ xdst, unsigned short* __restrict__ wdst,
    int n8x, int n8tot)
{
  int i = blockIdx.x * 256 + threadIdx.x;
  if (i >= n8tot) return;
  const float* src;
  unsigned short* dst;
  int idx;
  if (i < n8x) { src = xsrc; dst = xdst; idx = i; }
  else         { src = wsrc; dst = wdst; idx = i - n8x; }
  float4 v0 = ((const float4*)src)[2*idx];
  float4 v1 = ((const float4*)src)[2*idx + 1];
  uint4 pk;
  pk.x = (unsigned)f2h(v0.x) | ((unsigned)f2h(v0.y) << 16);
  pk.y = (unsigned)f2h(v0.z) | ((unsigned)f2h(v0.w) << 16);
  pk.z = (unsigned)f2h(v1.x) | ((unsigned)f2h(v1.y) << 16);
  pk.w = (unsigned)f2h(v1.z) | ((unsigned)f2h(v1.w) << 16);
  ((uint4*)dst)[idx] = pk;
}

// ---------------------------------------------------------------------------
// Kernel 1: merged QKV GEMM, 128x128 tile, BK=32, TRIPLE-buffered LDS, one
// fenced barrier per K-step, STATICALLY unrolled x3 (all buffer indices are
// literals -> no runtime-select VALU, LDS addrs fold; round-4 lesson).
// XCD swizzle: 768 blocks -> 8 chunks of 96 = 12bx x 8by each (bijective),
// so one XCD's resident blocks share ~3MB of W + ~2MB of A panels in its L2.
//   bxl <  16: QK[m][n] = x·W^T + b   (Q columns pre-scaled by QSCALE)
//   bxl >= 16: V blocks with OPERANDS SWAPPED (A = W_v rows, B = x rows) so
//             D = W_v·x^T = V^T, written straight into VT[(b*16+h)*64+d][s].
// No setprio (m190: hurts lockstep GEMM).
// ---------------------------------------------------------------------------
__global__ __launch_bounds__(256) void qkv_gemm_mfma(
    const unsigned short* __restrict__ Xh,
    const unsigned short* __restrict__ Wh,
    const float* __restrict__ bias,
    unsigned short* __restrict__ QK,
    unsigned short* __restrict__ VT)
{
  __shared__ unsigned short As[3][128][32];   // 24 KB
  __shared__ unsigned short Bs[3][128][32];   // 24 KB

  const int tid  = threadIdx.x;
  const int wave = tid >> 6;
  const int lane = tid & 63;
  const int l15  = lane & 15;
  const int quad = lane >> 4;

  // ---- XCD-aware swizzle: chunk c = 12bx x 8by on XCD (lin&7) ----
  const int lin = blockIdx.x + blockIdx.y * 24;      // dispatch order, x fastest
  const int c   = lin & 7;                           // XCD (round-robin claim)
  const int w   = lin >> 3;                          // 0..95 within chunk
  const int bxl = (c & 1) * 12 + (w % 12);
  const int byl = (c >> 1) * 8 + (w / 12);

  const bool isV = (bxl >= (NQK/128));
  const int n0 = (isV ? (bxl - NQK/128) : bxl) * 128;
  const int m0 = byl * 128;

  const unsigned short* Arows = isV ? (Wh + (size_t)(NQK + n0) * K_TOT)
                                    : (Xh + (size_t)m0 * K_TOT);
  const unsigned short* Brows = isV ? (Xh + (size_t)m0 * K_TOT)
                                    : (Wh + (size_t)n0 * K_TOT);

  const int srow = tid >> 2;            // 0..63
  const int skc  = (tid & 3) * 8;       // 0,8,16,24
  const unsigned short* Ag0 = Arows + (size_t)srow * K_TOT + skc;
  const unsigned short* Ag1 = Arows + (size_t)(64 + srow) * K_TOT + skc;
  const unsigned short* Bg0 = Brows + (size_t)srow * K_TOT + skc;
  const unsigned short* Bg1 = Brows + (size_t)(64 + srow) * K_TOT + skc;
  unsigned short* Al = &As[0][0][0] + tid * 8;   // buffer stride 4096 shorts
  unsigned short* Bl = &Bs[0][0][0] + tid * 8;

  const int wm = (wave & 1) * 64;
  const int wn = (wave >> 1) * 64;

  f32x4 acc[4][4];
  #pragma unroll
  for (int i = 0; i < 4; ++i)
    #pragma unroll
    for (int j = 0; j < 4; ++j) acc[i][j] = (f32x4){0.f,0.f,0.f,0.f};

  auto STAGE = [&](int k0, int bb) {               // bb must be a literal
    async16(Ag0 + k0, Al + bb*4096);
    async16(Ag1 + k0, Al + bb*4096 + 2048);
    async16(Bg0 + k0, Bl + bb*4096);
    async16(Bg1 + k0, Bl + bb*4096 + 2048);
  };

  auto COMPUTE = [&](int bb) {                     // bb must be a literal
    f16x8 af[4], bf[4];
    #pragma unroll
    for (int i = 0; i < 4; ++i)
      af[i] = *(const f16x8*)&As[bb][wm + i*16 + l15][quad*8];
    #pragma unroll
    for (int j = 0; j < 4; ++j)
      bf[j] = *(const f16x8*)&Bs[bb][wn + j*16 + l15][quad*8];
    #pragma unroll
    for (int i = 0; i < 4; ++i)
      #pragma unroll
      for (int j = 0; j < 4; ++j)
        acc[i][j] = __builtin_amdgcn_mfma_f32_16x16x32_f16(af[i], bf[j], acc[i][j], 0, 0, 0);
  };

  // tile t lives in buffer t%3; one fenced barrier per K-step
  #define G_KSTEP(t, sb, cb) \
    asm volatile("s_waitcnt vmcnt(4)" ::: "memory"); \
    barrier_f(); \
    STAGE(((t)+2)*32, (sb)); \
    COMPUTE((cb));

  STAGE(0, 0);
  STAGE(32, 1);
  for (int t = 0; t < 30; t += 3) {
    G_KSTEP(t,   2, 0)
    G_KSTEP(t+1, 0, 1)
    G_KSTEP(t+2, 1, 2)
  }
  asm volatile("s_waitcnt vmcnt(4)" ::: "memory");
  barrier_f();
  COMPUTE(0);                                      // tile 30
  asm volatile("s_waitcnt vmcnt(0)" ::: "memory");
  barrier_f();
  COMPUTE(1);                                      // tile 31
  #undef G_KSTEP

  if (!isV) {
    // D: col(l15) = n (weight), row(quad*4+r) = m (x row)
    const float sc = (n0 < DMODEL) ? QSCALE : 1.0f;
    float bv[4];
    #pragma unroll
    for (int j = 0; j < 4; ++j) bv[j] = bias[n0 + wn + j*16 + l15];
    #pragma unroll
    for (int i = 0; i < 4; ++i)
      #pragma unroll
      for (int j = 0; j < 4; ++j)
        #pragma unroll
        for (int r = 0; r < 4; ++r) {
          const size_t row = (size_t)(m0 + wm + i*16 + quad*4 + r);
          QK[row * NQK + n0 + wn + j*16 + l15] = f2h((acc[i][j][r] + bv[j]) * sc);
        }
  } else {
    // swapped: D col(l15) = x row (seq), D row(quad*4+r) = weight row (V col)
    const int bidx  = m0 >> 11;              // batch (m tiles don't straddle 2048)
    const int sbase = (m0 & 2047) + wn;
    #pragma unroll
    for (int i = 0; i < 4; ++i)
      #pragma unroll
      for (int r = 0; r < 4; ++r) {
        const int nn = n0 + wm + i*16 + quad*4 + r;         // V col 0..1023
        const float bb = bias[NQK + nn];
        unsigned short* drow =
            VT + ((size_t)(bidx*NH + (nn >> 6)) * HD + (nn & 63)) * SEQ + sbase;
        #pragma unroll
        for (int j = 0; j < 4; ++j)
          drow[j*16 + l15] = f2h(acc[i][j][r] + bb);        // 16 consecutive s
      }
  }
}

// ---------------------------------------------------------------------------
// Kernel 2: flash attention, 32x32x16 MFMA — round-1 proven structure
// (double-buffered K/V, counted vmcnt(4), 2 barriers/tile) with:
//  - static x2 unroll (literal buffer indices)
//  - XCD swizzle: (lin&7)*64 + lin>>3 -> each XCD runs 4 complete heads,
//    K/V working set 2MB fits its 4MB L2
//  - dsum split into 4 accumulators (breaks the 32-deep serial fp-add chain)
// Q pre-scaled by QSCALE in the GEMM -> softmax is bare exp2f.
// K/V LDS layouts linear [64][64]; logical col-group g lives at phys (g+row)&7.
// ---------------------------------------------------------------------------
__global__ __launch_bounds__(256) void attn_mfma3(
    const unsigned short* __restrict__ QK,
    const unsigned short* __restrict__ VT,
    float* __restrict__ out)
{
  __shared__ unsigned short Ks[2][64][64];   // 16 KB  [buf][key][d swz]
  __shared__ unsigned short Vs[2][64][64];   // 16 KB  [buf][d][key swz]
  __shared__ unsigned short Ps[4][32][72];   // 18 KB  [wave][q][key swz]
  __shared__ float Dn[4][32];

  const int tid  = threadIdx.x;
  const int wv   = tid >> 6;
  const int lane = tid & 63;
  const int l31  = lane & 31;
  const int h32  = lane >> 5;
  const int qsw  = l31 >> 3;

  // ---- XCD-aware swizzle: 512 blocks -> 8 chunks of 64 (4 heads each) ----
  const int lin = blockIdx.x + ((blockIdx.y + (blockIdx.z << 4)) << 4);
  const int logical = ((lin & 7) << 6) + (lin >> 3);
  const int qt   = logical & 15;             // fastest within chunk: same head
  const int head = logical >> 4;             // 0..31
  const int hh   = head & 15;
  const int b    = head >> 4;
  const int q0 = qt*128 + wv*32;

  // Q B-frags straight from global (pre-scaled)
  f16x8 qf[4];
  {
    const unsigned short* qrow = QK + (size_t)(b*SEQ + q0 + l31) * NQK + hh*HD;
    #pragma unroll
    for (int f = 0; f < 4; ++f)
      qf[f] = *(const f16x8*)(qrow + f*16 + h32*8);
  }

  const unsigned short* Kg = QK + (size_t)b*SEQ*NQK + DMODEL + hh*HD;
  const unsigned short* Vg = VT + (size_t)(b*NH + hh) * HD * SEQ;

  const int sr = tid >> 3;
  const int sp = tid & 7;
  const int sg = ((sp - sr) & 7) * 8;

  const unsigned short* kg0 = Kg + (size_t)sr      * NQK + sg;
  const unsigned short* kg1 = Kg + (size_t)(sr+32) * NQK + sg;
  const unsigned short* vg0 = Vg + (size_t)sr      * SEQ + sg;
  const unsigned short* vg1 = Vg + (size_t)(sr+32) * SEQ + sg;
  unsigned short* kl = &Ks[0][0][0] + tid*8;
  unsigned short* vl = &Vs[0][0][0] + tid*8;

  f32x16 oacc[2];
  oacc[0] = zero16();
  oacc[1] = zero16();
  float dsv[4] = {0.f, 0.f, 0.f, 0.f};       // 4-way split denominator accum

  auto STAGE = [&](int kt, int bb) {           // bb must be a literal
    const size_t krow = (size_t)kt * 64 * NQK; // K: advance rows (keys)
    const int    kcol = kt * 64;               // V^T: advance cols (keys)
    async16(kg0 + krow, kl + bb*4096);
    async16(kg1 + krow, kl + bb*4096 + 2048);
    async16(vg0 + kcol, vl + bb*4096);
    async16(vg1 + kcol, vl + bb*4096 + 2048);
  };

  auto COMPUTE = [&](int bb) {                 // bb must be a literal
    const unsigned short* ks = &Ks[bb][0][0];
    const unsigned short* vs = &Vs[bb][0][0];

    // ---- S^T = K.Q^T : rows=key (2 blocks of 32), cols=q ----
    f32x16 sa[2];
    sa[0] = zero16();
    sa[1] = zero16();
    __builtin_amdgcn_s_setprio(1);
    #pragma unroll
    for (int f = 0; f < 4; ++f) {
      const int g = f*2 + h32;
      #pragma unroll
      for (int kb = 0; kb < 2; ++kb) {
        const int row = kb*32 + l31;
        f16x8 kf = *(const f16x8*)(ks + row*64 + ((g + row) & 7) * 8);
        sa[kb] = __builtin_amdgcn_mfma_f32_32x32x16_f16(kf, qf[f], sa[kb], 0, 0, 0);
      }
    }
    __builtin_amdgcn_s_setprio(0);

    // ---- exp2 (scale pre-folded), split denom accum, P -> LDS ----
    #pragma unroll
    for (int kb = 0; kb < 2; ++kb) {
      #pragma unroll
      for (int g4 = 0; g4 < 4; ++g4) {
        unsigned short hsv[4];
        #pragma unroll
        for (int r = 0; r < 4; ++r) {
          float p = exp2f(sa[kb][g4*4 + r]);
          dsv[r] += p;                      // 4 independent chains, 8 adds each
          hsv[r] = f2h(p);
        }
        unsigned short* dst =
            &Ps[wv][l31][(((kb*4 + g4) ^ qsw) & 7) * 8 + h32*4];
        uint2 pk;
        pk.x = (unsigned)hsv[0] | ((unsigned)hsv[1] << 16);
        pk.y = (unsigned)hsv[2] | ((unsigned)hsv[3] << 16);
        *(uint2*)dst = pk;   // same-wave write->read: lgkmcnt ordering suffices
      }
    }

    // ---- O += P.V : A = P[q][key], B = Vs[d][key] ----
    __builtin_amdgcn_s_setprio(1);
    #pragma unroll
    for (int f = 0; f < 4; ++f) {
      const int g = f*2 + h32;
      f16x8 pf = *(const f16x8*)&Ps[wv][l31][((g ^ qsw) & 7) * 8];
      #pragma unroll
      for (int jd = 0; jd < 2; ++jd) {
        const int row = jd*32 + l31;
        f16x8 vf = *(const f16x8*)(vs + row*64 + ((g + row) & 7) * 8);
        oacc[jd] = __builtin_amdgcn_mfma_f32_32x32x16_f16(pf, vf, oacc[jd], 0, 0, 0);
      }
    }
    __builtin_amdgcn_s_setprio(0);
  };

  // tile t lives in buffer t&1; 2 fenced barriers per tile (round-1 proven)
  #define A_STEP(kt, sb, cb) \
    STAGE((kt)+1, (sb)); \
    asm volatile("s_waitcnt vmcnt(4)" ::: "memory"); \
    barrier_f(); \
    COMPUTE((cb)); \
    barrier_f();

  STAGE(0, 0);
  for (int kt = 0; kt < 30; kt += 2) {
    A_STEP(kt,   1, 0)
    A_STEP(kt+1, 0, 1)
  }
  A_STEP(30, 1, 0)
  asm volatile("s_waitcnt vmcnt(0)" ::: "memory");
  barrier_f();
  COMPUTE(1);                                      // tile 31
  #undef A_STEP

  // ---- denom: combine split accums + the two half-wave partials (same q) ----
  float dsum = (dsv[0] + dsv[1]) + (dsv[2] + dsv[3]);
  dsum += __shfl_xor(dsum, 32, 64);
  Dn[wv][l31] = 1.f / dsum;          // wave-local; lgkmcnt ordering suffices

  // ---- write O: row q = g4*8 + h32*4 + r, col d = jd*32 + l31 ----
  #pragma unroll
  for (int jd = 0; jd < 2; ++jd) {
    #pragma unroll
    for (int g4 = 0; g4 < 4; ++g4) {
      #pragma unroll
      for (int r = 0; r < 4; ++r) {
        const int qrow = g4*8 + h32*4 + r;
        const float oval = oacc[jd][g4*4 + r] * Dn[wv][qrow];
        out[(size_t)(b*SEQ + q0 + qrow) * DMODEL + hh*HD + jd*32 + l31] = oval;
      }
    }
  }
}

extern "C" void kernel_launch(void* const* d_in, const int* in_sizes, int n_in,
                              void* d_out, int out_size, void* d_ws, size_t ws_size,
                              hipStream_t stream) {
  const float* x    = (const float*)d_in[0];   // [2,2048,1024] fp32
  const float* W    = (const float*)d_in[1];   // [3072,1024]   fp32
  const float* bias = (const float*)d_in[2];   // [3072]        fp32
  float* out = (float*)d_out;                  // [2,2048,1024] fp32

  unsigned short* qk = (unsigned short*)d_ws;                   // 4096*2048 f16 (Q scaled | K)
  unsigned short* vt = qk + (size_t)M_TOT * NQK;                // [2*16][64][2048] f16 = V^T
  unsigned short* xh = vt + (size_t)BATCH * NH * HD * SEQ;      // 4096*1024 f16
  unsigned short* wh = xh + (size_t)M_TOT * K_TOT;              // 3072*1024 f16

  const int n8x = M_TOT*K_TOT/8;               // 524288
  const int n8w = N_TOT*K_TOT/8;               // 393216
  cast_f16_2<<<(n8x + n8w + 255)/256, 256, 0, stream>>>(x, W, xh, wh, n8x, n8x + n8w);

  dim3 g1(N_TOT/128, M_TOT/128);               // 24 x 32 = 768 blocks (16 QK + 8 V)
  qkv_gemm_mfma<<<g1, 256, 0, stream>>>(xh, wh, bias, qk, vt);

  dim3 g2(SEQ/128, NH, BATCH);                 // 16 x 16 x 2 = 512 blocks
  attn_mfma3<<<g2, 256, 0, stream>>>(qk, vt, out);
}

// Round 6
// 181.907 us; speedup vs baseline: 1.0590x; 1.0070x over previous
//
#include <hip/hip_runtime.h>

#define BATCH 2
#define SEQ 2048
#define DMODEL 1024
#define NH 16
#define HD 64
#define M_TOT (BATCH*SEQ)   // 4096
#define N_TOT (3*DMODEL)    // 3072
#define K_TOT (DMODEL)      // 1024
#define NQK   (2*DMODEL)    // 2048  (Q|K buffer width)
// 1/sqrt(64) * log2(e), folded into Q at the GEMM epilogue -> softmax is bare exp2
#define QSCALE 0.18033688011112042f

typedef __attribute__((ext_vector_type(8)))  _Float16 f16x8;
typedef __attribute__((ext_vector_type(4)))  float    f32x4;
typedef __attribute__((ext_vector_type(16))) float    f32x16;
typedef __attribute__((ext_vector_type(2)))  unsigned u32x2;

static __device__ __forceinline__ unsigned short f2h(float f) {
  _Float16 h = (_Float16)f;        // v_cvt_f16_f32, RTNE
  return __builtin_bit_cast(unsigned short, h);
}

static __device__ __forceinline__ unsigned pk2h(float a, float b) {
  return (unsigned)f2h(a) | ((unsigned)f2h(b) << 16);
}

static __device__ __forceinline__ f32x16 zero16() {
  f32x16 z;
  #pragma unroll
  for (int i = 0; i < 16; ++i) z[i] = 0.f;
  return z;
}

// async 16B global->LDS (wave-uniform LDS base + lane*16 layout required;
// the GLOBAL source is per-lane -> swizzled LDS layouts via pre-swizzled src)
static __device__ __forceinline__ void async16(const unsigned short* g, unsigned short* l) {
  __builtin_amdgcn_global_load_lds(
      (const __attribute__((address_space(1))) unsigned*)g,
      (__attribute__((address_space(3))) unsigned*)l, 16, 0, 0);
}

// Raw s_barrier is IntrNoMem: memory ops can legally move across it (round-3
// race). IR-level memory-clobber fences pin all memory ops to their side of
// the barrier. NO sched_barrier(0) (round-4 regression, m141 failure mode).
static __device__ __forceinline__ void barrier_f() {
  asm volatile("" ::: "memory");
  __builtin_amdgcn_s_barrier();
  asm volatile("" ::: "memory");
}

// ---------------------------------------------------------------------------
// Kernel 0: fp32 -> fp16 cast for BOTH x and W in one launch (8 elems/thread)
// ---------------------------------------------------------------------------
__global__ __launch_bounds__(256) void cast_f16_2(
    const float* __restrict__ xsrc, const float* __restrict__ wsrc,
    unsigned short* __restrict__ xdst, unsigned short* __restrict__ wdst,
    int n8x, int n8tot)
{
  int i = blockIdx.x * 256 + threadIdx.x;
  if (i >= n8tot) return;
  const float* src;
  unsigned short* dst;
  int idx;
  if (i < n8x) { src = xsrc; dst = xdst; idx = i; }
  else         { src = wsrc; dst = wdst; idx = i - n8x; }
  float4 v0 = ((const float4*)src)[2*idx];
  float4 v1 = ((const float4*)src)[2*idx + 1];
  uint4 pk;
  pk.x = (unsigned)f2h(v0.x) | ((unsigned)f2h(v0.y) << 16);
  pk.y = (unsigned)f2h(v0.z) | ((unsigned)f2h(v0.w) << 16);
  pk.z = (unsigned)f2h(v1.x) | ((unsigned)f2h(v1.y) << 16);
  pk.w = (unsigned)f2h(v1.z) | ((unsigned)f2h(v1.w) << 16);
  ((uint4*)dst)[idx] = pk;
}

// ---------------------------------------------------------------------------
// Kernel 1: merged QKV GEMM — UNCHANGED from round 5 (isolating the attn
// change this round). 128x128 tile, BK=32, triple-buffered LDS, one fenced
// barrier per K-step, statically unrolled x3, XCD-swizzled grid.
// ---------------------------------------------------------------------------
__global__ __launch_bounds__(256) void qkv_gemm_mfma(
    const unsigned short* __restrict__ Xh,
    const unsigned short* __restrict__ Wh,
    const float* __restrict__ bias,
    unsigned short* __restrict__ QK,
    unsigned short* __restrict__ VT)
{
  __shared__ unsigned short As[3][128][32];   // 24 KB
  __shared__ unsigned short Bs[3][128][32];   // 24 KB

  const int tid  = threadIdx.x;
  const int wave = tid >> 6;
  const int lane = tid & 63;
  const int l15  = lane & 15;
  const int quad = lane >> 4;

  // ---- XCD-aware swizzle: chunk c = 12bx x 8by on XCD (lin&7) ----
  const int lin = blockIdx.x + blockIdx.y * 24;      // dispatch order, x fastest
  const int c   = lin & 7;                           // XCD (round-robin claim)
  const int w   = lin >> 3;                          // 0..95 within chunk
  const int bxl = (c & 1) * 12 + (w % 12);
  const int byl = (c >> 1) * 8 + (w / 12);

  const bool isV = (bxl >= (NQK/128));
  const int n0 = (isV ? (bxl - NQK/128) : bxl) * 128;
  const int m0 = byl * 128;

  const unsigned short* Arows = isV ? (Wh + (size_t)(NQK + n0) * K_TOT)
                                    : (Xh + (size_t)m0 * K_TOT);
  const unsigned short* Brows = isV ? (Xh + (size_t)m0 * K_TOT)
                                    : (Wh + (size_t)n0 * K_TOT);

  const int srow = tid >> 2;            // 0..63
  const int skc  = (tid & 3) * 8;       // 0,8,16,24
  const unsigned short* Ag0 = Arows + (size_t)srow * K_TOT + skc;
  const unsigned short* Ag1 = Arows + (size_t)(64 + srow) * K_TOT + skc;
  const unsigned short* Bg0 = Brows + (size_t)srow * K_TOT + skc;
  const unsigned short* Bg1 = Brows + (size_t)(64 + srow) * K_TOT + skc;
  unsigned short* Al = &As[0][0][0] + tid * 8;   // buffer stride 4096 shorts
  unsigned short* Bl = &Bs[0][0][0] + tid * 8;

  const int wm = (wave & 1) * 64;
  const int wn = (wave >> 1) * 64;

  f32x4 acc[4][4];
  #pragma unroll
  for (int i = 0; i < 4; ++i)
    #pragma unroll
    for (int j = 0; j < 4; ++j) acc[i][j] = (f32x4){0.f,0.f,0.f,0.f};

  auto STAGE = [&](int k0, int bb) {               // bb must be a literal
    async16(Ag0 + k0, Al + bb*4096);
    async16(Ag1 + k0, Al + bb*4096 + 2048);
    async16(Bg0 + k0, Bl + bb*4096);
    async16(Bg1 + k0, Bl + bb*4096 + 2048);
  };

  auto COMPUTE = [&](int bb) {                     // bb must be a literal
    f16x8 af[4], bf[4];
    #pragma unroll
    for (int i = 0; i < 4; ++i)
      af[i] = *(const f16x8*)&As[bb][wm + i*16 + l15][quad*8];
    #pragma unroll
    for (int j = 0; j < 4; ++j)
      bf[j] = *(const f16x8*)&Bs[bb][wn + j*16 + l15][quad*8];
    #pragma unroll
    for (int i = 0; i < 4; ++i)
      #pragma unroll
      for (int j = 0; j < 4; ++j)
        acc[i][j] = __builtin_amdgcn_mfma_f32_16x16x32_f16(af[i], bf[j], acc[i][j], 0, 0, 0);
  };

  // tile t lives in buffer t%3; one fenced barrier per K-step
  #define G_KSTEP(t, sb, cb) \
    asm volatile("s_waitcnt vmcnt(4)" ::: "memory"); \
    barrier_f(); \
    STAGE(((t)+2)*32, (sb)); \
    COMPUTE((cb));

  STAGE(0, 0);
  STAGE(32, 1);
  for (int t = 0; t < 30; t += 3) {
    G_KSTEP(t,   2, 0)
    G_KSTEP(t+1, 0, 1)
    G_KSTEP(t+2, 1, 2)
  }
  asm volatile("s_waitcnt vmcnt(4)" ::: "memory");
  barrier_f();
  COMPUTE(0);                                      // tile 30
  asm volatile("s_waitcnt vmcnt(0)" ::: "memory");
  barrier_f();
  COMPUTE(1);                                      // tile 31
  #undef G_KSTEP

  if (!isV) {
    // D: col(l15) = n (weight), row(quad*4+r) = m (x row)
    const float sc = (n0 < DMODEL) ? QSCALE : 1.0f;
    float bv[4];
    #pragma unroll
    for (int j = 0; j < 4; ++j) bv[j] = bias[n0 + wn + j*16 + l15];
    #pragma unroll
    for (int i = 0; i < 4; ++i)
      #pragma unroll
      for (int j = 0; j < 4; ++j)
        #pragma unroll
        for (int r = 0; r < 4; ++r) {
          const size_t row = (size_t)(m0 + wm + i*16 + quad*4 + r);
          QK[row * NQK + n0 + wn + j*16 + l15] = f2h((acc[i][j][r] + bv[j]) * sc);
        }
  } else {
    // swapped: D col(l15) = x row (seq), D row(quad*4+r) = weight row (V col)
    const int bidx  = m0 >> 11;              // batch (m tiles don't straddle 2048)
    const int sbase = (m0 & 2047) + wn;
    #pragma unroll
    for (int i = 0; i < 4; ++i)
      #pragma unroll
      for (int r = 0; r < 4; ++r) {
        const int nn = n0 + wm + i*16 + quad*4 + r;         // V col 0..1023
        const float bb = bias[NQK + nn];
        unsigned short* drow =
            VT + ((size_t)(bidx*NH + (nn >> 6)) * HD + (nn & 63)) * SEQ + sbase;
        #pragma unroll
        for (int j = 0; j < 4; ++j)
          drow[j*16 + l15] = f2h(acc[i][j][r] + bb);        // 16 consecutive s
      }
  }
}

// ---------------------------------------------------------------------------
// Kernel 2: flash attention, 32x32x16 MFMA.
// P NEVER touches LDS (T12): after swapped QK^T, lane L holds P[q=L&31] for
// keys r+8s+4*h32. The PV A-frag word pairs are built with v_cvt pack (RTNE,
// identical numerics to the LDS path) and exchanged across the lane<32/>=32
// split with v_permlane32_swap_b32 (VALU pipe, m255: 1.20x vs DS-permute;
// round-2's shfl_xor attempt was the same routing on the DS pipe).
//   swap(X0,Y0) -> r[0] = {X0 own | Y0 partner} = pf word0 (keys 16f+8h+{0,1})
//                  r[1] = {X0 partner | Y0 own} = pf word2 (keys 16f+8h+{4,5})
// Word-by-word identical to round-2's PASSING assembly -> same absmax.
// This deletes the Ps buffer: the only bank-conflicted LDS access (stride-144B
// writes, 4-way) and 12 DS ops/tile/wave on the serial softmax->PV path.
// Structure otherwise = round 5: double-buffered K/V via pre-swizzled
// global_load_lds, counted vmcnt(4), 2 fenced barriers/tile, static x2
// unroll, XCD swizzle (FETCH 69.7->12.4MB measured), 4-way split dsum.
// ---------------------------------------------------------------------------
__global__ __launch_bounds__(256) void attn_mfma3(
    const unsigned short* __restrict__ QK,
    const unsigned short* __restrict__ VT,
    float* __restrict__ out)
{
  __shared__ unsigned short Ks[2][64][64];   // 16 KB  [buf][key][d swz]
  __shared__ unsigned short Vs[2][64][64];   // 16 KB  [buf][d][key swz]
  __shared__ float Dn[4][32];

  const int tid  = threadIdx.x;
  const int wv   = tid >> 6;
  const int lane = tid & 63;
  const int l31  = lane & 31;
  const int h32  = lane >> 5;

  // ---- XCD-aware swizzle: 512 blocks -> 8 chunks of 64 (4 heads each) ----
  const int lin = blockIdx.x + ((blockIdx.y + (blockIdx.z << 4)) << 4);
  const int logical = ((lin & 7) << 6) + (lin >> 3);
  const int qt   = logical & 15;             // fastest within chunk: same head
  const int head = logical >> 4;             // 0..31
  const int hh   = head & 15;
  const int b    = head >> 4;
  const int q0 = qt*128 + wv*32;

  // Q B-frags straight from global (pre-scaled)
  f16x8 qf[4];
  {
    const unsigned short* qrow = QK + (size_t)(b*SEQ + q0 + l31) * NQK + hh*HD;
    #pragma unroll
    for (int f = 0; f < 4; ++f)
      qf[f] = *(const f16x8*)(qrow + f*16 + h32*8);
  }

  const unsigned short* Kg = QK + (size_t)b*SEQ*NQK + DMODEL + hh*HD;
  const unsigned short* Vg = VT + (size_t)(b*NH + hh) * HD * SEQ;

  const int sr = tid >> 3;
  const int sp = tid & 7;
  const int sg = ((sp - sr) & 7) * 8;

  const unsigned short* kg0 = Kg + (size_t)sr      * NQK + sg;
  const unsigned short* kg1 = Kg + (size_t)(sr+32) * NQK + sg;
  const unsigned short* vg0 = Vg + (size_t)sr      * SEQ + sg;
  const unsigned short* vg1 = Vg + (size_t)(sr+32) * SEQ + sg;
  unsigned short* kl = &Ks[0][0][0] + tid*8;
  unsigned short* vl = &Vs[0][0][0] + tid*8;

  f32x16 oacc[2];
  oacc[0] = zero16();
  oacc[1] = zero16();
  float dsv[4] = {0.f, 0.f, 0.f, 0.f};       // 4-way split denominator accum

  auto STAGE = [&](int kt, int bb) {           // bb must be a literal
    const size_t krow = (size_t)kt * 64 * NQK; // K: advance rows (keys)
    const int    kcol = kt * 64;               // V^T: advance cols (keys)
    async16(kg0 + krow, kl + bb*4096);
    async16(kg1 + krow, kl + bb*4096 + 2048);
    async16(vg0 + kcol, vl + bb*4096);
    async16(vg1 + kcol, vl + bb*4096 + 2048);
  };

  auto COMPUTE = [&](int bb) {                 // bb must be a literal
    const unsigned short* ks = &Ks[bb][0][0];
    const unsigned short* vs = &Vs[bb][0][0];

    // ---- S^T = K.Q^T : rows=key (2 blocks of 32), cols=q ----
    f32x16 sa[2];
    sa[0] = zero16();
    sa[1] = zero16();
    __builtin_amdgcn_s_setprio(1);
    #pragma unroll
    for (int f = 0; f < 4; ++f) {
      const int g = f*2 + h32;
      #pragma unroll
      for (int kb = 0; kb < 2; ++kb) {
        const int row = kb*32 + l31;
        f16x8 kf = *(const f16x8*)(ks + row*64 + ((g + row) & 7) * 8);
        sa[kb] = __builtin_amdgcn_mfma_f32_32x32x16_f16(kf, qf[f], sa[kb], 0, 0, 0);
      }
    }
    __builtin_amdgcn_s_setprio(0);

    // ---- exp2 (scale pre-folded) in place + split denom accum ----
    #pragma unroll
    for (int kb = 0; kb < 2; ++kb)
      #pragma unroll
      for (int i = 0; i < 16; ++i) {
        float p = exp2f(sa[kb][i]);
        dsv[i & 3] += p;                   // 4 independent chains
        sa[kb][i] = p;
      }

    // ---- O += P.V : P A-frags fully in registers (pack + permlane swap) ----
    // Lane owns keys 16f+4h+{0,1}(X0) {2,3}(X1) and 16f+8+4h+{0,1}(Y0)
    // {2,3}(Y1); swap gives each half its missing partner runs.
    __builtin_amdgcn_s_setprio(1);
    #pragma unroll
    for (int f = 0; f < 4; ++f) {
      const int kb = f >> 1;
      const int s0 = (f & 1) * 8;
      unsigned X0 = pk2h(sa[kb][s0+0], sa[kb][s0+1]);
      unsigned X1 = pk2h(sa[kb][s0+2], sa[kb][s0+3]);
      unsigned Y0 = pk2h(sa[kb][s0+4], sa[kb][s0+5]);
      unsigned Y1 = pk2h(sa[kb][s0+6], sa[kb][s0+7]);
      u32x2 r0 = __builtin_amdgcn_permlane32_swap(X0, Y0, false, false);
      u32x2 r1 = __builtin_amdgcn_permlane32_swap(X1, Y1, false, false);
      uint4 pw;
      pw.x = r0[0];   // keys 16f+8h+{0,1}
      pw.y = r1[0];   // keys 16f+8h+{2,3}
      pw.z = r0[1];   // keys 16f+8h+{4,5}
      pw.w = r1[1];   // keys 16f+8h+{6,7}
      f16x8 pf = __builtin_bit_cast(f16x8, pw);
      const int g = f*2 + h32;
      #pragma unroll
      for (int jd = 0; jd < 2; ++jd) {
        const int row = jd*32 + l31;
        f16x8 vf = *(const f16x8*)(vs + row*64 + ((g + row) & 7) * 8);
        oacc[jd] = __builtin_amdgcn_mfma_f32_32x32x16_f16(pf, vf, oacc[jd], 0, 0, 0);
      }
    }
    __builtin_amdgcn_s_setprio(0);
  };

  // tile t lives in buffer t&1; 2 fenced barriers per tile (round-1 proven)
  #define A_STEP(kt, sb, cb) \
    STAGE((kt)+1, (sb)); \
    asm volatile("s_waitcnt vmcnt(4)" ::: "memory"); \
    barrier_f(); \
    COMPUTE((cb)); \
    barrier_f();

  STAGE(0, 0);
  for (int kt = 0; kt < 30; kt += 2) {
    A_STEP(kt,   1, 0)
    A_STEP(kt+1, 0, 1)
  }
  A_STEP(30, 1, 0)
  asm volatile("s_waitcnt vmcnt(0)" ::: "memory");
  barrier_f();
  COMPUTE(1);                                      // tile 31
  #undef A_STEP

  // ---- denom: combine split accums + the two half-wave partials (same q) ----
  float dsum = (dsv[0] + dsv[1]) + (dsv[2] + dsv[3]);
  dsum += __shfl_xor(dsum, 32, 64);
  Dn[wv][l31] = 1.f / dsum;          // wave-local; lgkmcnt ordering suffices

  // ---- write O: row q = g4*8 + h32*4 + r, col d = jd*32 + l31 ----
  #pragma unroll
  for (int jd = 0; jd < 2; ++jd) {
    #pragma unroll
    for (int g4 = 0; g4 < 4; ++g4) {
      #pragma unroll
      for (int r = 0; r < 4; ++r) {
        const int qrow = g4*8 + h32*4 + r;
        const float oval = oacc[jd][g4*4 + r] * Dn[wv][qrow];
        out[(size_t)(b*SEQ + q0 + qrow) * DMODEL + hh*HD + jd*32 + l31] = oval;
      }
    }
  }
}

extern "C" void kernel_launch(void* const* d_in, const int* in_sizes, int n_in,
                              void* d_out, int out_size, void* d_ws, size_t ws_size,
                              hipStream_t stream) {
  const float* x    = (const float*)d_in[0];   // [2,2048,1024] fp32
  const float* W    = (const float*)d_in[1];   // [3072,1024]   fp32
  const float* bias = (const float*)d_in[2];   // [3072]        fp32
  float* out = (float*)d_out;                  // [2,2048,1024] fp32

  unsigned short* qk = (unsigned short*)d_ws;                   // 4096*2048 f16 (Q scaled | K)
  unsigned short* vt = qk + (size_t)M_TOT * NQK;                // [2*16][64][2048] f16 = V^T
  unsigned short* xh = vt + (size_t)BATCH * NH * HD * SEQ;      // 4096*1024 f16
  unsigned short* wh = xh + (size_t)M_TOT * K_TOT;              // 3072*1024 f16

  const int n8x = M_TOT*K_TOT/8;               // 524288
  const int n8w = N_TOT*K_TOT/8;               // 393216
  cast_f16_2<<<(n8x + n8w + 255)/256, 256, 0, stream>>>(x, W, xh, wh, n8x, n8x + n8w);

  dim3 g1(N_TOT/128, M_TOT/128);               // 24 x 32 = 768 blocks (16 QK + 8 V)
  qkv_gemm_mfma<<<g1, 256, 0, stream>>>(xh, wh, bias, qk, vt);

  dim3 g2(SEQ/128, NH, BATCH);                 // 16 x 16 x 2 = 512 blocks
  attn_mfma3<<<g2, 256, 0, stream>>>(qk, vt, out);
}